// Round 7
// baseline (264.974 us; speedup 1.0000x reference)
//
#include <hip/hip_runtime.h>

#define B_ROWS   16384
#define D_DIM    2048
#define L_LAYERS 6

#define PRE_THREADS 1024

// workspace layout (floats): U[0..2047], e[2048..2053], pad, c[2064..18447]
#define WS_U_OFF   0
#define WS_E_OFF   D_DIM
#define WS_C_OFF   (D_DIM + 16)              // 16B-aligned
#define WS_FLOATS  (WS_C_OFF + B_ROWS)

// pass 1: 2 rows/wave, streaming dot (nothing retained)
#define P1_THREADS 256
#define P1_WAVES   (P1_THREADS / 64)
#define P1_ROWS_PER_WAVE 2
#define P1_BLOCKS  (B_ROWS / (P1_WAVES * P1_ROWS_PER_WAVE))   // 2048

// pass 2: grid-stride copy-shaped apply
#define P2_THREADS 256
#define P2_BLOCKS  4096
#define P2_TOTAL_F4 (B_ROWS * (D_DIM / 4))   // 8388608
#define P2_STRIDE   (P2_BLOCKS * P2_THREADS) // 1048576
#define P2_ITERS    (P2_TOTAL_F4 / P2_STRIDE) // 8

typedef float f32x4 __attribute__((ext_vector_type(4)));

// Exact algebra: x_l = c_l*x0 + u_l, u_l = sum_{i<l} b_i,
//   c_{l+1} = c_l*(1 + x0.W_l) + u_l.W_l.
// Whole net = 6 dots/row + scalar recurrence + out = c*x0 + U.
//
// R8: three structurally different FUSED kernels (R0 regs / R3 L2-W /
// R7 streaming) all plateau at 85-90us, 2.3-3.0 TB/s, with clean
// counters (no spill, no conflicts, minimal traffic). Remaining theory:
// the fused read-epoch -> reduce -> write-epoch structure (forced by the
// row dependency of c) never presents the memory system with the steady
// bidirectional stream a copy kernel uses to hit 6.3 TB/s. Split into
// phase-pure passes:
//   pass1: streaming dot, nothing retained, no LDS, W from L2 ->
//          32 waves/CU of pure x read; writes only c[16384] to ws.
//   pass2: out = c[row]*x + U  -- literal grid-stride copy+FMA; x is
//          L3-hot from pass1; NT stores keep out from evicting x (next
//          bench iteration's pass1 then reads x from L3).
// Each dispatch is individually comparable to the copy roofline.

// ---- kernel A: U = sum_i b_i ; e[l] = (sum_{i<l} b_i) . W_l ----
__global__ __launch_bounds__(PRE_THREADS) void precompute_Ue(
    const float* __restrict__ W,
    const float* __restrict__ b,
    float* __restrict__ ws)
{
    __shared__ float red[PRE_THREADS / 64][L_LAYERS];
    const int t    = threadIdx.x;
    const int lane = t & 63;
    const int wid  = t >> 6;
    const int base = t * 2;                        // 1024 x 2 = 2048

    float2 prefix = make_float2(0.f, 0.f);
    float e_red[L_LAYERS];
    #pragma unroll
    for (int l = 0; l < L_LAYERS; ++l) {
        const float2 wv = *(const float2*)(W + l * D_DIM + base);
        const float2 bv = *(const float2*)(b + l * D_DIM + base);
        e_red[l] = prefix.x * wv.x + prefix.y * wv.y;   // prefix BEFORE b_l
        prefix.x += bv.x; prefix.y += bv.y;
    }
    *(float2*)(ws + WS_U_OFF + base) = prefix;     // U
    #pragma unroll
    for (int l = 0; l < L_LAYERS; ++l) {
        float v = e_red[l];
        #pragma unroll
        for (int off = 32; off >= 1; off >>= 1) v += __shfl_xor(v, off, 64);
        if (lane == 0) red[wid][l] = v;
    }
    __syncthreads();
    if (t < L_LAYERS) {
        float s = 0.f;
        #pragma unroll
        for (int w = 0; w < PRE_THREADS / 64; ++w) s += red[w][t];
        ws[WS_E_OFF + t] = s;                      // e[l]
    }
}

// ---- pass 1: c[row] for all rows; pure read stream ----
__global__ __launch_bounds__(P1_THREADS) void pass1_dots(
    const float* __restrict__ x,
    const float* __restrict__ W,
    const float* __restrict__ ws_in,   // U,e (read)
    float* __restrict__ ws_c)          // c (write)
{
    const int t    = threadIdx.x;
    const int lane = t & 63;
    const int wid  = t >> 6;
    const int gw   = blockIdx.x * P1_WAVES + wid;
    const size_t r0 = (size_t)gw * P1_ROWS_PER_WAVE;
    const float* xr0 = x + r0 * D_DIM;
    const float* xr1 = xr0 + D_DIM;
    const int eoff = lane * 4;                     // + j*256, j=0..7

    float p0[L_LAYERS], p1[L_LAYERS];
    #pragma unroll
    for (int l = 0; l < L_LAYERS; ++l) { p0[l] = 0.f; p1[l] = 0.f; }

    // streaming: consume-on-arrival, nothing retained. unroll 2 bounds
    // in-flight regs (~16 float4) -- R4 lesson: full batch -> spill.
    #pragma unroll 2
    for (int j = 0; j < 8; ++j) {
        const float4 xv0 = *(const float4*)(xr0 + j * 256 + eoff);
        const float4 xv1 = *(const float4*)(xr1 + j * 256 + eoff);
        #pragma unroll
        for (int l = 0; l < L_LAYERS; ++l) {
            const float4 wv = *(const float4*)(W + l * D_DIM + j * 256 + eoff);
            p0[l] += xv0.x * wv.x + xv0.y * wv.y + xv0.z * wv.z + xv0.w * wv.w;
            p1[l] += xv1.x * wv.x + xv1.y * wv.y + xv1.z * wv.z + xv1.w * wv.w;
        }
    }

    #pragma unroll
    for (int off = 32; off >= 1; off >>= 1) {
        #pragma unroll
        for (int l = 0; l < L_LAYERS; ++l) {
            p0[l] += __shfl_xor(p0[l], off, 64);
            p1[l] += __shfl_xor(p1[l], off, 64);
        }
    }

    float c0 = 1.f, c1 = 1.f;
    #pragma unroll
    for (int l = 0; l < L_LAYERS; ++l) {
        const float el = ws_in[WS_E_OFF + l];      // uniform broadcast load
        c0 = c0 * (1.f + p0[l]) + el;
        c1 = c1 * (1.f + p1[l]) + el;
    }
    if (lane == 0) {
        ws_c[r0]     = c0;
        ws_c[r0 + 1] = c1;
    }
}

// ---- pass 2: out = c[row]*x + U ; copy-shaped grid-stride ----
__global__ __launch_bounds__(P2_THREADS) void pass2_apply(
    const float* __restrict__ x,
    const float* __restrict__ ws,      // U at 0, c at WS_C_OFF
    float* __restrict__ out)
{
    const f32x4* x4 = (const f32x4*)x;
    const f32x4* U4 = (const f32x4*)(ws + WS_U_OFF);
    const float* cv = ws + WS_C_OFF;
    f32x4* o4 = (f32x4*)out;

    const int tid = blockIdx.x * P2_THREADS + threadIdx.x;
    #pragma unroll 2
    for (int k = 0; k < P2_ITERS; ++k) {
        const int i   = tid + k * P2_STRIDE;
        const int row = i >> 9;                    // 512 float4 per row
        const int d4  = i & 511;
        const float c = cv[row];                   // wave-broadcast (L2)
        const f32x4 xv = x4[i];                    // L3-hot from pass1
        const f32x4 uv = U4[d4];                   // L2-hot 8KB
        const f32x4 o = c * xv + uv;
        __builtin_nontemporal_store(o, &o4[i]);    // don't evict x from L3
    }
}

// ---- fallback (no usable workspace): R7 fused kernel, proven correct ----
#define FB_THREADS 512
#define FB_WPB     (FB_THREADS / 64)
#define FB_ROWS_PER_WAVE 4
#define FB_BLOCKS  (B_ROWS / (FB_ROWS_PER_WAVE * FB_WPB))

__global__ __launch_bounds__(FB_THREADS) void cross_rows_fb(
    const float* __restrict__ x,
    const float* __restrict__ W,
    const float* __restrict__ b,
    float* __restrict__ out)
{
    __shared__ float Wl[L_LAYERS][D_DIM];
    __shared__ float Ul[D_DIM];
    __shared__ float eLs[L_LAYERS];
    __shared__ float red[FB_WPB][L_LAYERS];

    const int t    = threadIdx.x;
    const int lane = t & 63;
    const int wid  = t >> 6;
    const int sbase = t * 4;

    {
        float4 prefix = make_float4(0.f, 0.f, 0.f, 0.f);
        float e_red[L_LAYERS];
        #pragma unroll
        for (int l = 0; l < L_LAYERS; ++l) {
            const float4 wv = *(const float4*)(W + l * D_DIM + sbase);
            const float4 bv = *(const float4*)(b + l * D_DIM + sbase);
            e_red[l] = prefix.x * wv.x + prefix.y * wv.y
                     + prefix.z * wv.z + prefix.w * wv.w;
            prefix.x += bv.x; prefix.y += bv.y;
            prefix.z += bv.z; prefix.w += bv.w;
            *(float4*)&Wl[l][sbase] = wv;
        }
        *(float4*)&Ul[sbase] = prefix;
        #pragma unroll
        for (int l = 0; l < L_LAYERS; ++l) {
            float v = e_red[l];
            #pragma unroll
            for (int off = 32; off >= 1; off >>= 1) v += __shfl_xor(v, off, 64);
            if (lane == 0) red[wid][l] = v;
        }
        __syncthreads();
        if (t < L_LAYERS) {
            float s = 0.f;
            #pragma unroll
            for (int w = 0; w < FB_WPB; ++w) s += red[w][t];
            eLs[t] = s;
        }
    }
    __syncthreads();

    const int gw = blockIdx.x * FB_WPB + wid;
    const float* xr = x + (size_t)gw * FB_ROWS_PER_WAVE * D_DIM;
    float* orow     = out + (size_t)gw * FB_ROWS_PER_WAVE * D_DIM;
    const int eoff  = lane * 4;

    float p[FB_ROWS_PER_WAVE][L_LAYERS];
    #pragma unroll
    for (int r = 0; r < FB_ROWS_PER_WAVE; ++r)
        #pragma unroll
        for (int l = 0; l < L_LAYERS; ++l) p[r][l] = 0.f;

    #pragma unroll 2
    for (int j = 0; j < 8; ++j) {
        float4 wv[L_LAYERS];
        #pragma unroll
        for (int l = 0; l < L_LAYERS; ++l)
            wv[l] = *(const float4*)&Wl[l][j * 256 + eoff];
        #pragma unroll
        for (int r = 0; r < FB_ROWS_PER_WAVE; ++r) {
            const float4 xv = *(const float4*)(xr + (size_t)r * D_DIM + j * 256 + eoff);
            #pragma unroll
            for (int l = 0; l < L_LAYERS; ++l)
                p[r][l] += xv.x * wv[l].x + xv.y * wv[l].y
                         + xv.z * wv[l].z + xv.w * wv[l].w;
        }
    }

    #pragma unroll
    for (int off = 32; off >= 1; off >>= 1) {
        #pragma unroll
        for (int r = 0; r < FB_ROWS_PER_WAVE; ++r)
            #pragma unroll
            for (int l = 0; l < L_LAYERS; ++l)
                p[r][l] += __shfl_xor(p[r][l], off, 64);
    }

    float c[FB_ROWS_PER_WAVE];
    #pragma unroll
    for (int r = 0; r < FB_ROWS_PER_WAVE; ++r) {
        float cr = 1.f;
        #pragma unroll
        for (int l = 0; l < L_LAYERS; ++l)
            cr = cr * (1.f + p[r][l]) + eLs[l];
        c[r] = cr;
    }

    #pragma unroll 2
    for (int j = 0; j < 8; ++j) {
        const float4 uv = *(const float4*)&Ul[j * 256 + eoff];
        #pragma unroll
        for (int r = 0; r < FB_ROWS_PER_WAVE; ++r) {
            const size_t off2 = (size_t)r * D_DIM + j * 256 + eoff;
            const float4 xv = *(const float4*)(xr + off2);
            f32x4 o;
            o.x = c[r] * xv.x + uv.x; o.y = c[r] * xv.y + uv.y;
            o.z = c[r] * xv.z + uv.z; o.w = c[r] * xv.w + uv.w;
            __builtin_nontemporal_store(o, (f32x4*)(orow + off2));
        }
    }
}

extern "C" void kernel_launch(void* const* d_in, const int* in_sizes, int n_in,
                              void* d_out, int out_size, void* d_ws, size_t ws_size,
                              hipStream_t stream) {
    (void)in_sizes; (void)n_in; (void)out_size;
    const float* x = (const float*)d_in[0];
    const float* W = (const float*)d_in[1];
    const float* b = (const float*)d_in[2];
    float* out = (float*)d_out;

    const bool use_ws = (d_ws != nullptr) && (ws_size >= WS_FLOATS * sizeof(float));
    if (use_ws) {
        float* ws = (float*)d_ws;
        precompute_Ue<<<dim3(1), dim3(PRE_THREADS), 0, stream>>>(W, b, ws);
        pass1_dots<<<dim3(P1_BLOCKS), dim3(P1_THREADS), 0, stream>>>(
            x, W, ws, ws + WS_C_OFF);
        pass2_apply<<<dim3(P2_BLOCKS), dim3(P2_THREADS), 0, stream>>>(
            x, ws, out);
    } else {
        cross_rows_fb<<<dim3(FB_BLOCKS), dim3(FB_THREADS), 0, stream>>>(
            x, W, b, out);
    }
}

// Round 8
// 254.403 us; speedup vs baseline: 1.0415x; 1.0415x over previous
//
#include <hip/hip_runtime.h>

#define B_ROWS   16384
#define D_DIM    2048
#define L_LAYERS 6

#define THREADS  512                          // 8 waves/block
#define WPB      (THREADS / 64)
#define ROWS_PER_WAVE 4
#define TOTAL_WAVES (B_ROWS / ROWS_PER_WAVE)  // 4096
#define BLOCKS   (TOTAL_WAVES / WPB)          // 512
#define PRE_THREADS 1024
#define WS_FLOATS   (D_DIM + L_LAYERS)        // U[2048] + e[6]

typedef float f32x4 __attribute__((ext_vector_type(4)));

// Exact algebra: x_l = c_l*x0 + u_l, u_l = sum_{i<l} b_i,
//   c_{l+1} = c_l*(1 + x0.W_l) + u_l.W_l.
// Whole net = 6 dots/row + scalar recurrence + out = c*x0 + U.
//
// R9: session facts driving this version:
//  - bench = our kernels + ~163us of harness poison-fills (two 512MiB
//    fills at 6.7 TB/s visible in R8's top-5) -> only kernel time is ours.
//  - fills prove 6.7 TB/s is reachable; our fused best (R7: 88.6us) runs
//    3.0 TB/s with minimal traffic (268MB) and zero spill.
//  - avg outstanding bytes = 3.0e12*(900cy/2.4GHz)/256CU = 4.4KB/CU vs
//    ~9.2KB needed for 6.3 TB/s. Occupancy is LDS-bound ONLY because W's
//    48KB staging forces 2 blocks/CU.
//  - R8's split kernels (~103us sum) were worse than fused -> reverted.
// Single change vs R7-fused: W read from L2 (global) instead of LDS.
// LDS 57.8->8.4KB; occupancy becomes VGPR-bound (16->20+ waves/CU).
// W loads share the vmcnt FIFO with x loads but retire at L2 latency.
// Everything else identical (streaming consume-on-arrival Phase A,
// one butterfly per 4 rows, L3-hot x re-read Phase B, NT stores).

// ---- kernel A: U = sum_i b_i ; e[l] = (sum_{i<l} b_i) . W_l ----
__global__ __launch_bounds__(PRE_THREADS) void precompute_Ue(
    const float* __restrict__ W,
    const float* __restrict__ b,
    float* __restrict__ ws)
{
    __shared__ float red[PRE_THREADS / 64][L_LAYERS];
    const int t    = threadIdx.x;
    const int lane = t & 63;
    const int wid  = t >> 6;
    const int base = t * 2;                        // 1024 x 2 = 2048

    float2 prefix = make_float2(0.f, 0.f);
    float e_red[L_LAYERS];
    #pragma unroll
    for (int l = 0; l < L_LAYERS; ++l) {
        const float2 wv = *(const float2*)(W + l * D_DIM + base);
        const float2 bv = *(const float2*)(b + l * D_DIM + base);
        e_red[l] = prefix.x * wv.x + prefix.y * wv.y;   // prefix BEFORE b_l
        prefix.x += bv.x; prefix.y += bv.y;
    }
    *(float2*)(ws + base) = prefix;                // U
    #pragma unroll
    for (int l = 0; l < L_LAYERS; ++l) {
        float v = e_red[l];
        #pragma unroll
        for (int off = 32; off >= 1; off >>= 1) v += __shfl_xor(v, off, 64);
        if (lane == 0) red[wid][l] = v;
    }
    __syncthreads();
    if (t < L_LAYERS) {
        float s = 0.f;
        #pragma unroll
        for (int w = 0; w < PRE_THREADS / 64; ++w) s += red[w][t];
        ws[D_DIM + t] = s;                         // e[l]
    }
}

// ---- kernel B: 4 rows/wave streaming; W from L2, U from LDS ----
template <bool USE_WS>
__global__ __launch_bounds__(THREADS) void cross_rows(
    const float* __restrict__ x,
    const float* __restrict__ W,
    const float* __restrict__ b,
    const float* __restrict__ ws,
    float* __restrict__ out)
{
    __shared__ float Ul[D_DIM];                    // 8 KB (the ONLY big LDS)
    __shared__ float eLs[L_LAYERS];
    __shared__ float red[WPB][L_LAYERS];           // fallback only

    const int t    = threadIdx.x;
    const int lane = t & 63;
    const int wid  = t >> 6;
    const int sbase = t * 4;                       // 512 x 4 = 2048

    if constexpr (USE_WS) {
        *(float4*)&Ul[sbase] = *(const float4*)(ws + sbase);
        if (t < L_LAYERS) eLs[t] = ws[D_DIM + t];
    } else {
        float4 prefix = make_float4(0.f, 0.f, 0.f, 0.f);
        float e_red[L_LAYERS];
        #pragma unroll
        for (int l = 0; l < L_LAYERS; ++l) {
            const float4 wv = *(const float4*)(W + l * D_DIM + sbase);
            const float4 bv = *(const float4*)(b + l * D_DIM + sbase);
            e_red[l] = prefix.x * wv.x + prefix.y * wv.y
                     + prefix.z * wv.z + prefix.w * wv.w;  // prefix BEFORE b_l
            prefix.x += bv.x; prefix.y += bv.y;
            prefix.z += bv.z; prefix.w += bv.w;
        }
        *(float4*)&Ul[sbase] = prefix;
        #pragma unroll
        for (int l = 0; l < L_LAYERS; ++l) {
            float v = e_red[l];
            #pragma unroll
            for (int off = 32; off >= 1; off >>= 1) v += __shfl_xor(v, off, 64);
            if (lane == 0) red[wid][l] = v;
        }
        __syncthreads();
        if (t < L_LAYERS) {
            float s = 0.f;
            #pragma unroll
            for (int w = 0; w < WPB; ++w) s += red[w][t];
            eLs[t] = s;
        }
    }
    __syncthreads();

    const int gw = blockIdx.x * WPB + wid;
    const float* xr = x + (size_t)gw * ROWS_PER_WAVE * D_DIM;
    float* orow     = out + (size_t)gw * ROWS_PER_WAVE * D_DIM;
    const int eoff  = lane * 4;                    // + j*256, j=0..7

    // ---- Phase A: streaming dots; x consumed on arrival, never kept ----
    float p[ROWS_PER_WAVE][L_LAYERS];              // 24 accumulators
    #pragma unroll
    for (int r = 0; r < ROWS_PER_WAVE; ++r)
        #pragma unroll
        for (int l = 0; l < L_LAYERS; ++l) p[r][l] = 0.f;

    #pragma unroll 2
    for (int j = 0; j < 8; ++j) {
        float4 wv[L_LAYERS];                       // L2-resident, fast retire
        #pragma unroll
        for (int l = 0; l < L_LAYERS; ++l)
            wv[l] = *(const float4*)(W + l * D_DIM + j * 256 + eoff);
        #pragma unroll
        for (int r = 0; r < ROWS_PER_WAVE; ++r) {
            const float4 xv = *(const float4*)(xr + (size_t)r * D_DIM + j * 256 + eoff);
            #pragma unroll
            for (int l = 0; l < L_LAYERS; ++l)
                p[r][l] += xv.x * wv[l].x + xv.y * wv[l].y
                         + xv.z * wv[l].z + xv.w * wv[l].w;
        }
    }

    // ---- one butterfly reduce per 4 rows ----
    #pragma unroll
    for (int off = 32; off >= 1; off >>= 1) {
        #pragma unroll
        for (int r = 0; r < ROWS_PER_WAVE; ++r)
            #pragma unroll
            for (int l = 0; l < L_LAYERS; ++l)
                p[r][l] += __shfl_xor(p[r][l], off, 64);
    }

    float c[ROWS_PER_WAVE];
    #pragma unroll
    for (int r = 0; r < ROWS_PER_WAVE; ++r) {
        float cr = 1.f;
        #pragma unroll
        for (int l = 0; l < L_LAYERS; ++l)
            cr = cr * (1.f + p[r][l]) + eLs[l];
        c[r] = cr;
    }

    // ---- Phase B: apply-stream; x re-read is L3-hot (just touched) ----
    #pragma unroll 2
    for (int j = 0; j < 8; ++j) {
        const float4 uv = *(const float4*)&Ul[j * 256 + eoff];
        #pragma unroll
        for (int r = 0; r < ROWS_PER_WAVE; ++r) {
            const size_t off2 = (size_t)r * D_DIM + j * 256 + eoff;
            const float4 xv = *(const float4*)(xr + off2);
            f32x4 o;
            o.x = c[r] * xv.x + uv.x; o.y = c[r] * xv.y + uv.y;
            o.z = c[r] * xv.z + uv.z; o.w = c[r] * xv.w + uv.w;
            __builtin_nontemporal_store(o, (f32x4*)(orow + off2));
        }
    }
}

extern "C" void kernel_launch(void* const* d_in, const int* in_sizes, int n_in,
                              void* d_out, int out_size, void* d_ws, size_t ws_size,
                              hipStream_t stream) {
    (void)in_sizes; (void)n_in; (void)out_size;
    const float* x = (const float*)d_in[0];
    const float* W = (const float*)d_in[1];
    const float* b = (const float*)d_in[2];
    float* out = (float*)d_out;

    const bool use_ws = (d_ws != nullptr) && (ws_size >= WS_FLOATS * sizeof(float));
    if (use_ws) {
        float* ws = (float*)d_ws;
        precompute_Ue<<<dim3(1), dim3(PRE_THREADS), 0, stream>>>(W, b, ws);
        cross_rows<true><<<dim3(BLOCKS), dim3(THREADS), 0, stream>>>(
            x, W, b, ws, out);
    } else {
        cross_rows<false><<<dim3(BLOCKS), dim3(THREADS), 0, stream>>>(
            x, W, b, nullptr, out);
    }
}